// Round 10
// baseline (78.709 us; speedup 1.0000x reference)
//
#include <hip/hip_runtime.h>
#include <math.h>

#define NLEV   16
#define TSIZE  524288
#define TMASK  524287
#define NPIX   (1024*1024)
#define ENC_OFF_BYTES 32768

typedef __attribute__((ext_vector_type(8))) short s8v;
typedef __attribute__((ext_vector_type(4))) float f4v;

struct ResArr { float r[NLEV]; };
union Frag { unsigned int u[4]; s8v v; };

__device__ __forceinline__ unsigned short bf16_rn(float x) {
    unsigned int u = __builtin_bit_cast(unsigned int, x);
    u += 0x7fffu + ((u >> 16) & 1u);
    return (unsigned short)(u >> 16);
}
// truncating bf16 pack: one v_perm_b32 (values ~1e-4 vs 1e-2 threshold).
__device__ __forceinline__ unsigned int pk_bf16(float lo, float hi) {
    return __builtin_amdgcn_perm(__builtin_bit_cast(unsigned int, hi),
                                 __builtin_bit_cast(unsigned int, lo),
                                 0x07060302u);
}

// ws layout: [0..15] res f32. Then ushort region at ws+16:
//   w1t: W1^T bf16 [64][32]; w2t: W2^T k-permuted [64][64];
//   w3t: W3^T k-permuted row-replicated [16][64].
// At byte offset ENC_OFF_BYTES: enc buffer, u32 [NPIX][16] (64 MB), only used
// when ws_size permits (split path).
__global__ __launch_bounds__(256) void prep_kernel(
    const float* __restrict__ W1, const float* __restrict__ W2,
    const float* __restrict__ W3, float* __restrict__ ws, ResArr res)
{
    const int t = threadIdx.x;
    if (t < NLEV) ws[t] = res.r[t];
    unsigned short* w1t = (unsigned short*)(ws + 16);
    unsigned short* w2t = w1t + 64 * 32;
    unsigned short* w3t = w2t + 64 * 64;
    for (int i = t; i < 64 * 32; i += 256) {
        int n = i >> 5, k = i & 31;
        w1t[i] = bf16_rn(W1[k * 64 + n]);
    }
    for (int i = t; i < 64 * 64; i += 256) {
        int n2 = i >> 6, kp = i & 63;
        int klog = (kp & 32) | ((kp & 4) << 2) | ((kp & 24) >> 1) | (kp & 3);
        w2t[i] = bf16_rn(W2[klog * 64 + n2]);
    }
    for (int i = t; i < 16 * 64; i += 256) {
        int row = i >> 6, kp = i & 63;
        int klog = (kp & 32) | ((kp & 4) << 2) | ((kp & 24) >> 1) | (kp & 3);
        int ch = row & 3;
        w3t[i] = (ch < 3) ? bf16_rn(W3[klog * 3 + ch]) : (unsigned short)0;
    }
}

// ===================== split path: phase 1 (encode) =====================
// Latency-bound gather kernel: rely on TLP (default scheduler target = 8
// waves/SIMD; R9's waves_per_eu(4,4) capped occupancy at 50% and was the
// regression). Gathers use a WAVE-UNIFORM base pointer + u32 element index
// (level folded into the index) so the compiler emits saddr-form loads with
// no per-lane 64-bit address arithmetic.
// Writes enc[spatial_px][16 u32] in B-fragment word order (level pairs).
__global__ __launch_bounds__(256) void ngp_enc_kernel(
    const float* __restrict__ tables,
    const float* __restrict__ ws,
    unsigned int* __restrict__ enc)
{
    const int tid  = threadIdx.x;
    const int lane = tid & 63;
    const int wv   = tid >> 6;
    const int c15  = lane & 15;
    const int g    = lane >> 4;
    const int xb   = blockIdx.x * 16;
    const int yb   = blockIdx.y * 16;

    const float4 rv = *(const float4*)(ws + g * 4);
    const float rr[4] = { rv.x, rv.y, rv.z, rv.w };
    const float xs = (float)(xb + c15) * (1.0f / 1024.0f);
    float yf[4];
    #pragma unroll
    for (int pt = 0; pt < 4; ++pt)
        yf[pt] = (float)(yb + wv * 4 + pt) * (1.0f / 1024.0f);

    const float2* __restrict__ tabs = (const float2*)tables;  // uniform base
    const unsigned int gbase = (unsigned int)(g * 4) << 19;   // lane-varying index part

    float2 fb[2][4][4];
    float  fxb[2];
    float  fyb[2][4];
    Frag   bfrag[4];

#define ENC_ISSUE(J, B) do {                                                  \
    const float r_   = rr[J];                                                 \
    const float sx_  = xs * r_;                                               \
    const float fx0_ = floorf(sx_);                                           \
    fxb[B] = sx_ - fx0_;                                                      \
    const unsigned int cx_  = (unsigned int)fx0_;                             \
    const unsigned int cx1_ = cx_ + 1u;                                       \
    const unsigned int lvl_ = gbase + ((unsigned int)(J) << 19);              \
    _Pragma("unroll")                                                         \
    for (int pt_ = 0; pt_ < 4; ++pt_) {                                       \
        const float sy_  = yf[pt_] * r_;                                      \
        const float fy0_ = floorf(sy_);                                       \
        fyb[B][pt_] = sy_ - fy0_;                                             \
        const unsigned int cy_  = (unsigned int)fy0_;                         \
        const unsigned int hy0_ = cy_ * 2654435761u;                          \
        const unsigned int hy1_ = hy0_ + 2654435761u;                         \
        fb[B][pt_][0] = tabs[lvl_ + ((cx_  ^ hy0_) & TMASK)];                 \
        fb[B][pt_][1] = tabs[lvl_ + ((cx1_ ^ hy0_) & TMASK)];                 \
        fb[B][pt_][2] = tabs[lvl_ + ((cx_  ^ hy1_) & TMASK)];                 \
        fb[B][pt_][3] = tabs[lvl_ + ((cx1_ ^ hy1_) & TMASK)];                 \
    }                                                                         \
    asm volatile("" ::: "memory");                                            \
} while (0)

#define ENC_CONSUME(J, B) do {                                                \
    const float fx_ = fxb[B];                                                 \
    _Pragma("unroll")                                                         \
    for (int pt_ = 0; pt_ < 4; ++pt_) {                                       \
        const float fy_  = fyb[B][pt_];                                       \
        const float w00_ = (1.0f - fx_) * (1.0f - fy_);                       \
        const float w10_ = fx_          * (1.0f - fy_);                       \
        const float w01_ = (1.0f - fx_) * fy_;                                \
        const float w11_ = fx_          * fy_;                                \
        const float e0_ = w00_ * fb[B][pt_][0].x + w10_ * fb[B][pt_][1].x     \
                        + w01_ * fb[B][pt_][2].x + w11_ * fb[B][pt_][3].x;    \
        const float e1_ = w00_ * fb[B][pt_][0].y + w10_ * fb[B][pt_][1].y     \
                        + w01_ * fb[B][pt_][2].y + w11_ * fb[B][pt_][3].y;    \
        bfrag[pt_].u[J] = pk_bf16(e0_, e1_);                                  \
    }                                                                         \
} while (0)

    ENC_ISSUE(0, 0);
    ENC_ISSUE(1, 1);
    ENC_CONSUME(0, 0);
    ENC_ISSUE(2, 0);
    ENC_CONSUME(1, 1);
    ENC_ISSUE(3, 1);
    ENC_CONSUME(2, 0);
    ENC_CONSUME(3, 1);

#undef ENC_ISSUE
#undef ENC_CONSUME

    // store: per pt one dwordx4 (words g*4..g*4+3 of spatial pixel row);
    // a wave's 64 lanes cover a contiguous 1 KiB range per pt.
    #pragma unroll
    for (int pt = 0; pt < 4; ++pt) {
        const int row = ((yb + wv * 4 + pt) << 10) + xb + c15;
        *(uint4*)(enc + (size_t)row * 16 + g * 4) = *(const uint4*)&bfrag[pt];
    }
}

// ===================== split path: phase 2 (MLP) =====================
// Pure streaming GEMM: wave w handles 64 consecutive pixels. B-fragments load
// coalesced from enc; all three layers on MFMA with lane-local activation
// hand-off (k-permuted weights); phase-split accumulators (16 AGPRs peak).
__global__ __launch_bounds__(256) void ngp_mlp_kernel(
    const unsigned int* __restrict__ enc,
    const float* __restrict__ b1, const float* __restrict__ b2,
    const float* __restrict__ b3,
    const float* __restrict__ ws, float* __restrict__ out)
{
    const int tid  = threadIdx.x;
    const int lane = tid & 63;
    const int wv   = tid >> 6;
    const int c15  = lane & 15;
    const int g    = lane >> 4;
    const int base = (blockIdx.x * 4 + wv) * 64;

    Frag bfrag[4];
    #pragma unroll
    for (int pt = 0; pt < 4; ++pt)
        *(uint4*)&bfrag[pt] =
            *(const uint4*)(enc + (size_t)(base + pt * 16 + c15) * 16 + g * 4);

    const unsigned short* __restrict__ w1t = (const unsigned short*)(ws + 16);
    const unsigned short* __restrict__ w2t = w1t + 64 * 32;
    const unsigned short* __restrict__ w3t = w2t + 64 * 64;

    // layer 1
    unsigned int hp[4][4][2];
    #pragma unroll
    for (int mt = 0; mt < 4; ++mt) {
        Frag afr;
        afr.v = *(const s8v*)(w1t + (mt * 16 + c15) * 32 + g * 8);
        const float4 bb = *(const float4*)(b1 + mt * 16 + g * 4);
        #pragma unroll
        for (int pt = 0; pt < 4; ++pt) {
            f4v acc = (f4v){0.f, 0.f, 0.f, 0.f};
            acc = __builtin_amdgcn_mfma_f32_16x16x32_bf16(
                afr.v, bfrag[pt].v, acc, 0, 0, 0);
            const float v0 = fmaxf(acc[0] + bb.x, 0.0f);
            const float v1 = fmaxf(acc[1] + bb.y, 0.0f);
            const float v2 = fmaxf(acc[2] + bb.z, 0.0f);
            const float v3 = fmaxf(acc[3] + bb.w, 0.0f);
            hp[mt][pt][0] = pk_bf16(v0, v1);
            hp[mt][pt][1] = pk_bf16(v2, v3);
        }
    }

    // layer 2 (per-mt accumulator split)
    unsigned int hq[4][4][2];
    #pragma unroll
    for (int mt = 0; mt < 4; ++mt) {
        const float4 bb2 = *(const float4*)(b2 + mt * 16 + g * 4);
        f4v acc[4];
        #pragma unroll
        for (int pt = 0; pt < 4; ++pt) acc[pt] = (f4v){0.f, 0.f, 0.f, 0.f};
        #pragma unroll
        for (int st = 0; st < 2; ++st) {
            Frag a2, bf2[4];
            a2.v = *(const s8v*)(w2t + (mt * 16 + c15) * 64 + st * 32 + g * 8);
            #pragma unroll
            for (int pt = 0; pt < 4; ++pt) {
                bf2[pt].u[0] = hp[2 * st + 0][pt][0];
                bf2[pt].u[1] = hp[2 * st + 0][pt][1];
                bf2[pt].u[2] = hp[2 * st + 1][pt][0];
                bf2[pt].u[3] = hp[2 * st + 1][pt][1];
            }
            #pragma unroll
            for (int pt = 0; pt < 4; ++pt)
                acc[pt] = __builtin_amdgcn_mfma_f32_16x16x32_bf16(
                    a2.v, bf2[pt].v, acc[pt], 0, 0, 0);
        }
        #pragma unroll
        for (int pt = 0; pt < 4; ++pt) {
            const float v0 = fmaxf(acc[pt][0] + bb2.x, 0.0f);
            const float v1 = fmaxf(acc[pt][1] + bb2.y, 0.0f);
            const float v2 = fmaxf(acc[pt][2] + bb2.z, 0.0f);
            const float v3 = fmaxf(acc[pt][3] + bb2.w, 0.0f);
            hq[mt][pt][0] = pk_bf16(v0, v1);
            hq[mt][pt][1] = pk_bf16(v2, v3);
        }
    }

    // layer 3 on MFMA (row-replicated W3: reg r = channel r on every lane)
    f4v acc3[4];
    #pragma unroll
    for (int pt = 0; pt < 4; ++pt) acc3[pt] = (f4v){0.f, 0.f, 0.f, 0.f};
    #pragma unroll
    for (int st = 0; st < 2; ++st) {
        Frag a3, bf3[4];
        a3.v = *(const s8v*)(w3t + c15 * 64 + st * 32 + g * 8);
        #pragma unroll
        for (int pt = 0; pt < 4; ++pt) {
            bf3[pt].u[0] = hq[2 * st + 0][pt][0];
            bf3[pt].u[1] = hq[2 * st + 0][pt][1];
            bf3[pt].u[2] = hq[2 * st + 1][pt][0];
            bf3[pt].u[3] = hq[2 * st + 1][pt][1];
        }
        #pragma unroll
        for (int pt = 0; pt < 4; ++pt)
            acc3[pt] = __builtin_amdgcn_mfma_f32_16x16x32_bf16(
                a3.v, bf3[pt].v, acc3[pt], 0, 0, 0);
    }

    float ov[3];
    #pragma unroll
    for (int c = 0; c < 3; ++c) {
        float v = acc3[0][c];
        v = (g == 1) ? acc3[1][c] : v;
        v = (g == 2) ? acc3[2][c] : v;
        v = (g == 3) ? acc3[3][c] : v;
        ov[c] = v + b3[c];
    }
    const int pix = base + g * 16 + c15;
    out[0 * NPIX + pix] = 1.0f / (1.0f + __expf(-ov[0]));
    out[1 * NPIX + pix] = 1.0f / (1.0f + __expf(-ov[1]));
    out[2 * NPIX + pix] = 1.0f / (1.0f + __expf(-ov[2]));
}

// ===================== fallback: R8 fused kernel (verbatim) =====================
__global__ __launch_bounds__(256) void ngp_fused_kernel(
    const float* __restrict__ tables,
    const float* __restrict__ b1, const float* __restrict__ b2,
    const float* __restrict__ b3,
    const float* __restrict__ ws, float* __restrict__ out)
{
    const int tid  = threadIdx.x;
    const int lane = tid & 63;
    const int wv   = tid >> 6;
    const int c15  = lane & 15;
    const int g    = lane >> 4;
    const int xb   = blockIdx.x * 16;
    const int yb   = blockIdx.y * 16;

    const float4 rv = *(const float4*)(ws + g * 4);
    const float rr[4] = { rv.x, rv.y, rv.z, rv.w };
    const float xs = (float)(xb + c15) * (1.0f / 1024.0f);
    float yf[4];
    #pragma unroll
    for (int pt = 0; pt < 4; ++pt)
        yf[pt] = (float)(yb + wv * 4 + pt) * (1.0f / 1024.0f);

    const float2* __restrict__ tabg = (const float2*)tables + (size_t)(g * 4) * TSIZE;

    float2 fb[2][4][4];
    float  fxb[2];
    float  fyb[2][4];
    Frag   bfrag[4];

#define NGP_ISSUE(J, B) do {                                                  \
    const float r_   = rr[J];                                                 \
    const float sx_  = xs * r_;                                               \
    const float fx0_ = floorf(sx_);                                           \
    fxb[B] = sx_ - fx0_;                                                      \
    const unsigned int cx_  = (unsigned int)fx0_;                             \
    const unsigned int cx1_ = cx_ + 1u;                                       \
    const float2* __restrict__ tab_ = tabg + (size_t)(J) * TSIZE;             \
    _Pragma("unroll")                                                         \
    for (int pt_ = 0; pt_ < 4; ++pt_) {                                       \
        const float sy_  = yf[pt_] * r_;                                      \
        const float fy0_ = floorf(sy_);                                       \
        fyb[B][pt_] = sy_ - fy0_;                                             \
        const unsigned int cy_  = (unsigned int)fy0_;                         \
        const unsigned int hy0_ = cy_ * 2654435761u;                          \
        const unsigned int hy1_ = hy0_ + 2654435761u;                         \
        fb[B][pt_][0] = tab_[(cx_  ^ hy0_) & TMASK];                          \
        fb[B][pt_][1] = tab_[(cx1_ ^ hy0_) & TMASK];                          \
        fb[B][pt_][2] = tab_[(cx_  ^ hy1_) & TMASK];                          \
        fb[B][pt_][3] = tab_[(cx1_ ^ hy1_) & TMASK];                          \
    }                                                                         \
    asm volatile("" ::: "memory");                                            \
} while (0)

#define NGP_CONSUME(J, B) do {                                                \
    const float fx_ = fxb[B];                                                 \
    _Pragma("unroll")                                                         \
    for (int pt_ = 0; pt_ < 4; ++pt_) {                                       \
        const float fy_  = fyb[B][pt_];                                       \
        const float w00_ = (1.0f - fx_) * (1.0f - fy_);                       \
        const float w10_ = fx_          * (1.0f - fy_);                       \
        const float w01_ = (1.0f - fx_) * fy_;                                \
        const float w11_ = fx_          * fy_;                                \
        const float e0_ = w00_ * fb[B][pt_][0].x + w10_ * fb[B][pt_][1].x     \
                        + w01_ * fb[B][pt_][2].x + w11_ * fb[B][pt_][3].x;    \
        const float e1_ = w00_ * fb[B][pt_][0].y + w10_ * fb[B][pt_][1].y     \
                        + w01_ * fb[B][pt_][2].y + w11_ * fb[B][pt_][3].y;    \
        bfrag[pt_].u[J] = pk_bf16(e0_, e1_);                                  \
    }                                                                         \
} while (0)

    const unsigned short* __restrict__ w1t = (const unsigned short*)(ws + 16);
    const unsigned short* __restrict__ w2t = w1t + 64 * 32;
    const unsigned short* __restrict__ w3t = w2t + 64 * 64;
    Frag afr[4];

    NGP_ISSUE(0, 0);
    NGP_ISSUE(1, 1);
    NGP_CONSUME(0, 0);
    NGP_ISSUE(2, 0);
    NGP_CONSUME(1, 1);
    NGP_ISSUE(3, 1);
    #pragma unroll
    for (int mt = 0; mt < 4; ++mt)
        afr[mt].v = *(const s8v*)(w1t + (mt * 16 + c15) * 32 + g * 8);
    asm volatile("" ::: "memory");
    NGP_CONSUME(2, 0);
    NGP_CONSUME(3, 1);

#undef NGP_ISSUE
#undef NGP_CONSUME

    unsigned int hp[4][4][2];
    #pragma unroll
    for (int mt = 0; mt < 4; ++mt) {
        const float4 bb = *(const float4*)(b1 + mt * 16 + g * 4);
        #pragma unroll
        for (int pt = 0; pt < 4; ++pt) {
            f4v acc = (f4v){0.f, 0.f, 0.f, 0.f};
            acc = __builtin_amdgcn_mfma_f32_16x16x32_bf16(
                afr[mt].v, bfrag[pt].v, acc, 0, 0, 0);
            const float v0 = fmaxf(acc[0] + bb.x, 0.0f);
            const float v1 = fmaxf(acc[1] + bb.y, 0.0f);
            const float v2 = fmaxf(acc[2] + bb.z, 0.0f);
            const float v3 = fmaxf(acc[3] + bb.w, 0.0f);
            hp[mt][pt][0] = pk_bf16(v0, v1);
            hp[mt][pt][1] = pk_bf16(v2, v3);
        }
    }

    unsigned int hq[4][4][2];
    #pragma unroll
    for (int mt = 0; mt < 4; ++mt) {
        const float4 bb2 = *(const float4*)(b2 + mt * 16 + g * 4);
        f4v acc[4];
        #pragma unroll
        for (int pt = 0; pt < 4; ++pt) acc[pt] = (f4v){0.f, 0.f, 0.f, 0.f};
        #pragma unroll
        for (int st = 0; st < 2; ++st) {
            Frag a2, bf2[4];
            a2.v = *(const s8v*)(w2t + (mt * 16 + c15) * 64 + st * 32 + g * 8);
            #pragma unroll
            for (int pt = 0; pt < 4; ++pt) {
                bf2[pt].u[0] = hp[2 * st + 0][pt][0];
                bf2[pt].u[1] = hp[2 * st + 0][pt][1];
                bf2[pt].u[2] = hp[2 * st + 1][pt][0];
                bf2[pt].u[3] = hp[2 * st + 1][pt][1];
            }
            #pragma unroll
            for (int pt = 0; pt < 4; ++pt)
                acc[pt] = __builtin_amdgcn_mfma_f32_16x16x32_bf16(
                    a2.v, bf2[pt].v, acc[pt], 0, 0, 0);
        }
        #pragma unroll
        for (int pt = 0; pt < 4; ++pt) {
            const float v0 = fmaxf(acc[pt][0] + bb2.x, 0.0f);
            const float v1 = fmaxf(acc[pt][1] + bb2.y, 0.0f);
            const float v2 = fmaxf(acc[pt][2] + bb2.z, 0.0f);
            const float v3 = fmaxf(acc[pt][3] + bb2.w, 0.0f);
            hq[mt][pt][0] = pk_bf16(v0, v1);
            hq[mt][pt][1] = pk_bf16(v2, v3);
        }
    }

    f4v acc3[4];
    #pragma unroll
    for (int pt = 0; pt < 4; ++pt) acc3[pt] = (f4v){0.f, 0.f, 0.f, 0.f};
    #pragma unroll
    for (int st = 0; st < 2; ++st) {
        Frag a3, bf3[4];
        a3.v = *(const s8v*)(w3t + c15 * 64 + st * 32 + g * 8);
        #pragma unroll
        for (int pt = 0; pt < 4; ++pt) {
            bf3[pt].u[0] = hq[2 * st + 0][pt][0];
            bf3[pt].u[1] = hq[2 * st + 0][pt][1];
            bf3[pt].u[2] = hq[2 * st + 1][pt][0];
            bf3[pt].u[3] = hq[2 * st + 1][pt][1];
        }
        #pragma unroll
        for (int pt = 0; pt < 4; ++pt)
            acc3[pt] = __builtin_amdgcn_mfma_f32_16x16x32_bf16(
                a3.v, bf3[pt].v, acc3[pt], 0, 0, 0);
    }

    float ov[3];
    #pragma unroll
    for (int c = 0; c < 3; ++c) {
        float v = acc3[0][c];
        v = (g == 1) ? acc3[1][c] : v;
        v = (g == 2) ? acc3[2][c] : v;
        v = (g == 3) ? acc3[3][c] : v;
        ov[c] = v + b3[c];
    }
    const int pix = ((yb + wv * 4 + g) << 10) + xb + c15;
    out[0 * NPIX + pix] = 1.0f / (1.0f + __expf(-ov[0]));
    out[1 * NPIX + pix] = 1.0f / (1.0f + __expf(-ov[1]));
    out[2 * NPIX + pix] = 1.0f / (1.0f + __expf(-ov[2]));
}

extern "C" void kernel_launch(void* const* d_in, const int* in_sizes, int n_in,
                              void* d_out, int out_size, void* d_ws, size_t ws_size,
                              hipStream_t stream) {
    const float* tables = (const float*)d_in[0];
    const float* W1     = (const float*)d_in[1];
    const float* b1     = (const float*)d_in[2];
    const float* W2     = (const float*)d_in[3];
    const float* b2     = (const float*)d_in[4];
    const float* W3     = (const float*)d_in[5];
    const float* b3     = (const float*)d_in[6];
    float* out          = (float*)d_out;
    float* ws           = (float*)d_ws;

    ResArr res;
    const double growth = exp((log(1024.0) - log(16.0)) / 15.0);
    for (int l = 0; l < NLEV; ++l)
        res.r[l] = (float)floor(16.0 * pow(growth, (double)l));

    hipLaunchKernelGGL(prep_kernel, dim3(1), dim3(256), 0, stream, W1, W2, W3, ws, res);

    const size_t need = (size_t)ENC_OFF_BYTES + (size_t)NPIX * 64;
    if (ws_size >= need) {
        unsigned int* enc = (unsigned int*)((char*)d_ws + ENC_OFF_BYTES);
        hipLaunchKernelGGL(ngp_enc_kernel, dim3(64, 64), dim3(256), 0, stream,
                           tables, ws, enc);
        hipLaunchKernelGGL(ngp_mlp_kernel, dim3(4096), dim3(256), 0, stream,
                           enc, b1, b2, b3, ws, out);
    } else {
        hipLaunchKernelGGL(ngp_fused_kernel, dim3(64, 64), dim3(256), 0, stream,
                           tables, b1, b2, b3, ws, out);
    }
}

// Round 11
// 78.282 us; speedup vs baseline: 1.0055x; 1.0055x over previous
//
#include <hip/hip_runtime.h>
#include <math.h>

#define NLEV   16
#define TSIZE  524288
#define TMASK  524287
#define NPIX   (1024*1024)
#define ENC_OFF_BYTES 32768

typedef __attribute__((ext_vector_type(8))) short s8v;
typedef __attribute__((ext_vector_type(4))) float f4v;
typedef __attribute__((ext_vector_type(2))) float f2v;

struct ResArr { float r[NLEV]; };
union Frag { unsigned int u[4]; s8v v; };

__device__ __forceinline__ unsigned short bf16_rn(float x) {
    unsigned int u = __builtin_bit_cast(unsigned int, x);
    u += 0x7fffu + ((u >> 16) & 1u);
    return (unsigned short)(u >> 16);
}
// truncating bf16 pack: one v_perm_b32 (values ~1e-4 vs 1e-2 threshold).
__device__ __forceinline__ unsigned int pk_bf16(float lo, float hi) {
    return __builtin_amdgcn_perm(__builtin_bit_cast(unsigned int, hi),
                                 __builtin_bit_cast(unsigned int, lo),
                                 0x07060302u);
}

// Forced-in-flight gather: asm output MUST get a VGPR pair, so the compiler
// cannot serialize the batch (R5-R10: every source-level attempt was squeezed
// to ~2 outstanding loads). saddr form: uniform SGPR base + u32 byte offset.
// NOTE: result is NOT valid until an explicit s_waitcnt vmcnt(0).
__device__ __forceinline__ f2v gload2(const float* __restrict__ tab,
                                      unsigned int eidx) {
    f2v d;
    asm volatile("global_load_dwordx2 %0, %1, %2"
                 : "=v"(d)
                 : "v"(eidx << 3), "s"(tab));
    return d;
}

// ws layout: [0..15] res f32. Then ushort region at ws+16:
//   w1t: W1^T bf16 [64][32]; w2t: W2^T k-permuted [64][64];
//   w3t: W3^T k-permuted row-replicated [16][64].
// At byte offset ENC_OFF_BYTES: enc buffer, u32 [NPIX][16] (64 MB).
__global__ __launch_bounds__(256) void prep_kernel(
    const float* __restrict__ W1, const float* __restrict__ W2,
    const float* __restrict__ W3, float* __restrict__ ws, ResArr res)
{
    const int t = threadIdx.x;
    if (t < NLEV) ws[t] = res.r[t];
    unsigned short* w1t = (unsigned short*)(ws + 16);
    unsigned short* w2t = w1t + 64 * 32;
    unsigned short* w3t = w2t + 64 * 64;
    for (int i = t; i < 64 * 32; i += 256) {
        int n = i >> 5, k = i & 31;
        w1t[i] = bf16_rn(W1[k * 64 + n]);
    }
    for (int i = t; i < 64 * 64; i += 256) {
        int n2 = i >> 6, kp = i & 63;
        int klog = (kp & 32) | ((kp & 4) << 2) | ((kp & 24) >> 1) | (kp & 3);
        w2t[i] = bf16_rn(W2[klog * 64 + n2]);
    }
    for (int i = t; i < 16 * 64; i += 256) {
        int row = i >> 6, kp = i & 63;
        int klog = (kp & 32) | ((kp & 4) << 2) | ((kp & 24) >> 1) | (kp & 3);
        int ch = row & 3;
        w3t[i] = (ch < 3) ? bf16_rn(W3[klog * 3 + ch]) : (unsigned short)0;
    }
}

// ===================== split path: phase 1 (encode) =====================
// 32 loads genuinely in flight per wave via inline-asm gathers; two
// vmcnt(0)+sched_barrier(0) drains per wave. R10 showed TLP alone (62% occ)
// doesn't move the 45us: per-wave outstanding-load count is the lever.
__global__ __launch_bounds__(256) void ngp_enc_kernel(
    const float* __restrict__ tables,
    const float* __restrict__ ws,
    unsigned int* __restrict__ enc)
{
    const int tid  = threadIdx.x;
    const int lane = tid & 63;
    const int wv   = tid >> 6;
    const int c15  = lane & 15;
    const int g    = lane >> 4;
    const int xb   = blockIdx.x * 16;
    const int yb   = blockIdx.y * 16;

    const float4 rv = *(const float4*)(ws + g * 4);
    const float rr[4] = { rv.x, rv.y, rv.z, rv.w };
    const float xs = (float)(xb + c15) * (1.0f / 1024.0f);
    float yf[4];
    #pragma unroll
    for (int pt = 0; pt < 4; ++pt)
        yf[pt] = (float)(yb + wv * 4 + pt) * (1.0f / 1024.0f);

    const unsigned int gbase = (unsigned int)(g * 4) << 19;  // entry index part

    f2v   fb[2][4][4];
    float fxb[2];
    float fyb[2][4];
    Frag  bfrag[4];

#define ENC_ISSUE(J, B) do {                                                  \
    const float r_   = rr[J];                                                 \
    const float sx_  = xs * r_;                                               \
    const float fx0_ = floorf(sx_);                                           \
    fxb[B] = sx_ - fx0_;                                                      \
    const unsigned int cx_  = (unsigned int)fx0_;                             \
    const unsigned int cx1_ = cx_ + 1u;                                       \
    const unsigned int lvl_ = gbase + ((unsigned int)(J) << 19);              \
    _Pragma("unroll")                                                         \
    for (int pt_ = 0; pt_ < 4; ++pt_) {                                       \
        const float sy_  = yf[pt_] * r_;                                      \
        const float fy0_ = floorf(sy_);                                       \
        fyb[B][pt_] = sy_ - fy0_;                                             \
        const unsigned int cy_  = (unsigned int)fy0_;                         \
        const unsigned int hy0_ = cy_ * 2654435761u;                          \
        const unsigned int hy1_ = hy0_ + 2654435761u;                         \
        fb[B][pt_][0] = gload2(tables, lvl_ + ((cx_  ^ hy0_) & TMASK));       \
        fb[B][pt_][1] = gload2(tables, lvl_ + ((cx1_ ^ hy0_) & TMASK));       \
        fb[B][pt_][2] = gload2(tables, lvl_ + ((cx_  ^ hy1_) & TMASK));       \
        fb[B][pt_][3] = gload2(tables, lvl_ + ((cx1_ ^ hy1_) & TMASK));       \
    }                                                                         \
} while (0)

// The asm loads are invisible to the compiler's dependence tracking: the
// waitcnt makes the data real, the sched_barrier keeps consumers below it
// (guide rule #18).
#define ENC_WAIT() do {                                                       \
    asm volatile("s_waitcnt vmcnt(0)" ::: "memory");                          \
    __builtin_amdgcn_sched_barrier(0);                                        \
} while (0)

#define ENC_CONSUME(J, B) do {                                                \
    const float fx_ = fxb[B];                                                 \
    _Pragma("unroll")                                                         \
    for (int pt_ = 0; pt_ < 4; ++pt_) {                                       \
        const float fy_  = fyb[B][pt_];                                       \
        const float w00_ = (1.0f - fx_) * (1.0f - fy_);                       \
        const float w10_ = fx_          * (1.0f - fy_);                       \
        const float w01_ = (1.0f - fx_) * fy_;                                \
        const float w11_ = fx_          * fy_;                                \
        const float e0_ = w00_ * fb[B][pt_][0][0] + w10_ * fb[B][pt_][1][0]   \
                        + w01_ * fb[B][pt_][2][0] + w11_ * fb[B][pt_][3][0];  \
        const float e1_ = w00_ * fb[B][pt_][0][1] + w10_ * fb[B][pt_][1][1]   \
                        + w01_ * fb[B][pt_][2][1] + w11_ * fb[B][pt_][3][1];  \
        bfrag[pt_].u[J] = pk_bf16(e0_, e1_);                                  \
    }                                                                         \
} while (0)

    ENC_ISSUE(0, 0);
    ENC_ISSUE(1, 1);
    ENC_WAIT();
    ENC_CONSUME(0, 0);
    ENC_CONSUME(1, 1);
    ENC_ISSUE(2, 0);
    ENC_ISSUE(3, 1);
    ENC_WAIT();
    ENC_CONSUME(2, 0);
    ENC_CONSUME(3, 1);

#undef ENC_ISSUE
#undef ENC_WAIT
#undef ENC_CONSUME

    // store: per pt one dwordx4; a wave covers a contiguous 1 KiB per pt.
    #pragma unroll
    for (int pt = 0; pt < 4; ++pt) {
        const int row = ((yb + wv * 4 + pt) << 10) + xb + c15;
        *(uint4*)(enc + (size_t)row * 16 + g * 4) = *(const uint4*)&bfrag[pt];
    }
}

// ===================== split path: phase 2 (MLP) =====================
__global__ __launch_bounds__(256) void ngp_mlp_kernel(
    const unsigned int* __restrict__ enc,
    const float* __restrict__ b1, const float* __restrict__ b2,
    const float* __restrict__ b3,
    const float* __restrict__ ws, float* __restrict__ out)
{
    const int tid  = threadIdx.x;
    const int lane = tid & 63;
    const int wv   = tid >> 6;
    const int c15  = lane & 15;
    const int g    = lane >> 4;
    const int base = (blockIdx.x * 4 + wv) * 64;

    Frag bfrag[4];
    #pragma unroll
    for (int pt = 0; pt < 4; ++pt)
        *(uint4*)&bfrag[pt] =
            *(const uint4*)(enc + (size_t)(base + pt * 16 + c15) * 16 + g * 4);

    const unsigned short* __restrict__ w1t = (const unsigned short*)(ws + 16);
    const unsigned short* __restrict__ w2t = w1t + 64 * 32;
    const unsigned short* __restrict__ w3t = w2t + 64 * 64;

    // layer 1
    unsigned int hp[4][4][2];
    #pragma unroll
    for (int mt = 0; mt < 4; ++mt) {
        Frag afr;
        afr.v = *(const s8v*)(w1t + (mt * 16 + c15) * 32 + g * 8);
        const float4 bb = *(const float4*)(b1 + mt * 16 + g * 4);
        #pragma unroll
        for (int pt = 0; pt < 4; ++pt) {
            f4v acc = (f4v){0.f, 0.f, 0.f, 0.f};
            acc = __builtin_amdgcn_mfma_f32_16x16x32_bf16(
                afr.v, bfrag[pt].v, acc, 0, 0, 0);
            const float v0 = fmaxf(acc[0] + bb.x, 0.0f);
            const float v1 = fmaxf(acc[1] + bb.y, 0.0f);
            const float v2 = fmaxf(acc[2] + bb.z, 0.0f);
            const float v3 = fmaxf(acc[3] + bb.w, 0.0f);
            hp[mt][pt][0] = pk_bf16(v0, v1);
            hp[mt][pt][1] = pk_bf16(v2, v3);
        }
    }

    // layer 2 (per-mt accumulator split)
    unsigned int hq[4][4][2];
    #pragma unroll
    for (int mt = 0; mt < 4; ++mt) {
        const float4 bb2 = *(const float4*)(b2 + mt * 16 + g * 4);
        f4v acc[4];
        #pragma unroll
        for (int pt = 0; pt < 4; ++pt) acc[pt] = (f4v){0.f, 0.f, 0.f, 0.f};
        #pragma unroll
        for (int st = 0; st < 2; ++st) {
            Frag a2, bf2[4];
            a2.v = *(const s8v*)(w2t + (mt * 16 + c15) * 64 + st * 32 + g * 8);
            #pragma unroll
            for (int pt = 0; pt < 4; ++pt) {
                bf2[pt].u[0] = hp[2 * st + 0][pt][0];
                bf2[pt].u[1] = hp[2 * st + 0][pt][1];
                bf2[pt].u[2] = hp[2 * st + 1][pt][0];
                bf2[pt].u[3] = hp[2 * st + 1][pt][1];
            }
            #pragma unroll
            for (int pt = 0; pt < 4; ++pt)
                acc[pt] = __builtin_amdgcn_mfma_f32_16x16x32_bf16(
                    a2.v, bf2[pt].v, acc[pt], 0, 0, 0);
        }
        #pragma unroll
        for (int pt = 0; pt < 4; ++pt) {
            const float v0 = fmaxf(acc[pt][0] + bb2.x, 0.0f);
            const float v1 = fmaxf(acc[pt][1] + bb2.y, 0.0f);
            const float v2 = fmaxf(acc[pt][2] + bb2.z, 0.0f);
            const float v3 = fmaxf(acc[pt][3] + bb2.w, 0.0f);
            hq[mt][pt][0] = pk_bf16(v0, v1);
            hq[mt][pt][1] = pk_bf16(v2, v3);
        }
    }

    // layer 3 on MFMA (row-replicated W3: reg r = channel r on every lane)
    f4v acc3[4];
    #pragma unroll
    for (int pt = 0; pt < 4; ++pt) acc3[pt] = (f4v){0.f, 0.f, 0.f, 0.f};
    #pragma unroll
    for (int st = 0; st < 2; ++st) {
        Frag a3, bf3[4];
        a3.v = *(const s8v*)(w3t + c15 * 64 + st * 32 + g * 8);
        #pragma unroll
        for (int pt = 0; pt < 4; ++pt) {
            bf3[pt].u[0] = hq[2 * st + 0][pt][0];
            bf3[pt].u[1] = hq[2 * st + 0][pt][1];
            bf3[pt].u[2] = hq[2 * st + 1][pt][0];
            bf3[pt].u[3] = hq[2 * st + 1][pt][1];
        }
        #pragma unroll
        for (int pt = 0; pt < 4; ++pt)
            acc3[pt] = __builtin_amdgcn_mfma_f32_16x16x32_bf16(
                a3.v, bf3[pt].v, acc3[pt], 0, 0, 0);
    }

    float ov[3];
    #pragma unroll
    for (int c = 0; c < 3; ++c) {
        float v = acc3[0][c];
        v = (g == 1) ? acc3[1][c] : v;
        v = (g == 2) ? acc3[2][c] : v;
        v = (g == 3) ? acc3[3][c] : v;
        ov[c] = v + b3[c];
    }
    const int pix = base + g * 16 + c15;
    out[0 * NPIX + pix] = 1.0f / (1.0f + __expf(-ov[0]));
    out[1 * NPIX + pix] = 1.0f / (1.0f + __expf(-ov[1]));
    out[2 * NPIX + pix] = 1.0f / (1.0f + __expf(-ov[2]));
}

// ===================== fallback: R8 fused kernel (verbatim) =====================
__global__ __launch_bounds__(256) void ngp_fused_kernel(
    const float* __restrict__ tables,
    const float* __restrict__ b1, const float* __restrict__ b2,
    const float* __restrict__ b3,
    const float* __restrict__ ws, float* __restrict__ out)
{
    const int tid  = threadIdx.x;
    const int lane = tid & 63;
    const int wv   = tid >> 6;
    const int c15  = lane & 15;
    const int g    = lane >> 4;
    const int xb   = blockIdx.x * 16;
    const int yb   = blockIdx.y * 16;

    const float4 rv = *(const float4*)(ws + g * 4);
    const float rr[4] = { rv.x, rv.y, rv.z, rv.w };
    const float xs = (float)(xb + c15) * (1.0f / 1024.0f);
    float yf[4];
    #pragma unroll
    for (int pt = 0; pt < 4; ++pt)
        yf[pt] = (float)(yb + wv * 4 + pt) * (1.0f / 1024.0f);

    const float2* __restrict__ tabg = (const float2*)tables + (size_t)(g * 4) * TSIZE;

    float2 fb[2][4][4];
    float  fxb[2];
    float  fyb[2][4];
    Frag   bfrag[4];

#define NGP_ISSUE(J, B) do {                                                  \
    const float r_   = rr[J];                                                 \
    const float sx_  = xs * r_;                                               \
    const float fx0_ = floorf(sx_);                                           \
    fxb[B] = sx_ - fx0_;                                                      \
    const unsigned int cx_  = (unsigned int)fx0_;                             \
    const unsigned int cx1_ = cx_ + 1u;                                       \
    const float2* __restrict__ tab_ = tabg + (size_t)(J) * TSIZE;             \
    _Pragma("unroll")                                                         \
    for (int pt_ = 0; pt_ < 4; ++pt_) {                                       \
        const float sy_  = yf[pt_] * r_;                                      \
        const float fy0_ = floorf(sy_);                                       \
        fyb[B][pt_] = sy_ - fy0_;                                             \
        const unsigned int cy_  = (unsigned int)fy0_;                         \
        const unsigned int hy0_ = cy_ * 2654435761u;                          \
        const unsigned int hy1_ = hy0_ + 2654435761u;                         \
        fb[B][pt_][0] = tab_[(cx_  ^ hy0_) & TMASK];                          \
        fb[B][pt_][1] = tab_[(cx1_ ^ hy0_) & TMASK];                          \
        fb[B][pt_][2] = tab_[(cx_  ^ hy1_) & TMASK];                          \
        fb[B][pt_][3] = tab_[(cx1_ ^ hy1_) & TMASK];                          \
    }                                                                         \
    asm volatile("" ::: "memory");                                            \
} while (0)

#define NGP_CONSUME(J, B) do {                                                \
    const float fx_ = fxb[B];                                                 \
    _Pragma("unroll")                                                         \
    for (int pt_ = 0; pt_ < 4; ++pt_) {                                       \
        const float fy_  = fyb[B][pt_];                                       \
        const float w00_ = (1.0f - fx_) * (1.0f - fy_);                       \
        const float w10_ = fx_          * (1.0f - fy_);                       \
        const float w01_ = (1.0f - fx_) * fy_;                                \
        const float w11_ = fx_          * fy_;                                \
        const float e0_ = w00_ * fb[B][pt_][0].x + w10_ * fb[B][pt_][1].x     \
                        + w01_ * fb[B][pt_][2].x + w11_ * fb[B][pt_][3].x;    \
        const float e1_ = w00_ * fb[B][pt_][0].y + w10_ * fb[B][pt_][1].y     \
                        + w01_ * fb[B][pt_][2].y + w11_ * fb[B][pt_][3].y;    \
        bfrag[pt_].u[J] = pk_bf16(e0_, e1_);                                  \
    }                                                                         \
} while (0)

    const unsigned short* __restrict__ w1t = (const unsigned short*)(ws + 16);
    const unsigned short* __restrict__ w2t = w1t + 64 * 32;
    const unsigned short* __restrict__ w3t = w2t + 64 * 64;
    Frag afr[4];

    NGP_ISSUE(0, 0);
    NGP_ISSUE(1, 1);
    NGP_CONSUME(0, 0);
    NGP_ISSUE(2, 0);
    NGP_CONSUME(1, 1);
    NGP_ISSUE(3, 1);
    #pragma unroll
    for (int mt = 0; mt < 4; ++mt)
        afr[mt].v = *(const s8v*)(w1t + (mt * 16 + c15) * 32 + g * 8);
    asm volatile("" ::: "memory");
    NGP_CONSUME(2, 0);
    NGP_CONSUME(3, 1);

#undef NGP_ISSUE
#undef NGP_CONSUME

    unsigned int hp[4][4][2];
    #pragma unroll
    for (int mt = 0; mt < 4; ++mt) {
        const float4 bb = *(const float4*)(b1 + mt * 16 + g * 4);
        #pragma unroll
        for (int pt = 0; pt < 4; ++pt) {
            f4v acc = (f4v){0.f, 0.f, 0.f, 0.f};
            acc = __builtin_amdgcn_mfma_f32_16x16x32_bf16(
                afr[mt].v, bfrag[pt].v, acc, 0, 0, 0);
            const float v0 = fmaxf(acc[0] + bb.x, 0.0f);
            const float v1 = fmaxf(acc[1] + bb.y, 0.0f);
            const float v2 = fmaxf(acc[2] + bb.z, 0.0f);
            const float v3 = fmaxf(acc[3] + bb.w, 0.0f);
            hp[mt][pt][0] = pk_bf16(v0, v1);
            hp[mt][pt][1] = pk_bf16(v2, v3);
        }
    }

    unsigned int hq[4][4][2];
    #pragma unroll
    for (int mt = 0; mt < 4; ++mt) {
        const float4 bb2 = *(const float4*)(b2 + mt * 16 + g * 4);
        f4v acc[4];
        #pragma unroll
        for (int pt = 0; pt < 4; ++pt) acc[pt] = (f4v){0.f, 0.f, 0.f, 0.f};
        #pragma unroll
        for (int st = 0; st < 2; ++st) {
            Frag a2, bf2[4];
            a2.v = *(const s8v*)(w2t + (mt * 16 + c15) * 64 + st * 32 + g * 8);
            #pragma unroll
            for (int pt = 0; pt < 4; ++pt) {
                bf2[pt].u[0] = hp[2 * st + 0][pt][0];
                bf2[pt].u[1] = hp[2 * st + 0][pt][1];
                bf2[pt].u[2] = hp[2 * st + 1][pt][0];
                bf2[pt].u[3] = hp[2 * st + 1][pt][1];
            }
            #pragma unroll
            for (int pt = 0; pt < 4; ++pt)
                acc[pt] = __builtin_amdgcn_mfma_f32_16x16x32_bf16(
                    a2.v, bf2[pt].v, acc[pt], 0, 0, 0);
        }
        #pragma unroll
        for (int pt = 0; pt < 4; ++pt) {
            const float v0 = fmaxf(acc[pt][0] + bb2.x, 0.0f);
            const float v1 = fmaxf(acc[pt][1] + bb2.y, 0.0f);
            const float v2 = fmaxf(acc[pt][2] + bb2.z, 0.0f);
            const float v3 = fmaxf(acc[pt][3] + bb2.w, 0.0f);
            hq[mt][pt][0] = pk_bf16(v0, v1);
            hq[mt][pt][1] = pk_bf16(v2, v3);
        }
    }

    f4v acc3[4];
    #pragma unroll
    for (int pt = 0; pt < 4; ++pt) acc3[pt] = (f4v){0.f, 0.f, 0.f, 0.f};
    #pragma unroll
    for (int st = 0; st < 2; ++st) {
        Frag a3, bf3[4];
        a3.v = *(const s8v*)(w3t + c15 * 64 + st * 32 + g * 8);
        #pragma unroll
        for (int pt = 0; pt < 4; ++pt) {
            bf3[pt].u[0] = hq[2 * st + 0][pt][0];
            bf3[pt].u[1] = hq[2 * st + 0][pt][1];
            bf3[pt].u[2] = hq[2 * st + 1][pt][0];
            bf3[pt].u[3] = hq[2 * st + 1][pt][1];
        }
        #pragma unroll
        for (int pt = 0; pt < 4; ++pt)
            acc3[pt] = __builtin_amdgcn_mfma_f32_16x16x32_bf16(
                a3.v, bf3[pt].v, acc3[pt], 0, 0, 0);
    }

    float ov[3];
    #pragma unroll
    for (int c = 0; c < 3; ++c) {
        float v = acc3[0][c];
        v = (g == 1) ? acc3[1][c] : v;
        v = (g == 2) ? acc3[2][c] : v;
        v = (g == 3) ? acc3[3][c] : v;
        ov[c] = v + b3[c];
    }
    const int pix = ((yb + wv * 4 + g) << 10) + xb + c15;
    out[0 * NPIX + pix] = 1.0f / (1.0f + __expf(-ov[0]));
    out[1 * NPIX + pix] = 1.0f / (1.0f + __expf(-ov[1]));
    out[2 * NPIX + pix] = 1.0f / (1.0f + __expf(-ov[2]));
}

extern "C" void kernel_launch(void* const* d_in, const int* in_sizes, int n_in,
                              void* d_out, int out_size, void* d_ws, size_t ws_size,
                              hipStream_t stream) {
    const float* tables = (const float*)d_in[0];
    const float* W1     = (const float*)d_in[1];
    const float* b1     = (const float*)d_in[2];
    const float* W2     = (const float*)d_in[3];
    const float* b2     = (const float*)d_in[4];
    const float* W3     = (const float*)d_in[5];
    const float* b3     = (const float*)d_in[6];
    float* out          = (float*)d_out;
    float* ws           = (float*)d_ws;

    ResArr res;
    const double growth = exp((log(1024.0) - log(16.0)) / 15.0);
    for (int l = 0; l < NLEV; ++l)
        res.r[l] = (float)floor(16.0 * pow(growth, (double)l));

    hipLaunchKernelGGL(prep_kernel, dim3(1), dim3(256), 0, stream, W1, W2, W3, ws, res);

    const size_t need = (size_t)ENC_OFF_BYTES + (size_t)NPIX * 64;
    if (ws_size >= need) {
        unsigned int* enc = (unsigned int*)((char*)d_ws + ENC_OFF_BYTES);
        hipLaunchKernelGGL(ngp_enc_kernel, dim3(64, 64), dim3(256), 0, stream,
                           tables, ws, enc);
        hipLaunchKernelGGL(ngp_mlp_kernel, dim3(4096), dim3(256), 0, stream,
                           enc, b1, b2, b3, ws, out);
    } else {
        hipLaunchKernelGGL(ngp_fused_kernel, dim3(64, 64), dim3(256), 0, stream,
                           tables, b1, b2, b3, ws, out);
    }
}

// Round 12
// 77.287 us; speedup vs baseline: 1.0184x; 1.0129x over previous
//
#include <hip/hip_runtime.h>
#include <math.h>

#define NLEV   16
#define TSIZE  524288
#define TMASK  524287
#define NPIX   (1024*1024)

typedef __attribute__((ext_vector_type(8))) short s8v;
typedef __attribute__((ext_vector_type(4))) float f4v;

struct ResArr { float r[NLEV]; };
union Frag { unsigned int u[4]; s8v v; };

__device__ __forceinline__ unsigned short bf16_rn(float x) {
    unsigned int u = __builtin_bit_cast(unsigned int, x);
    u += 0x7fffu + ((u >> 16) & 1u);
    return (unsigned short)(u >> 16);
}
// truncating bf16 pack: one v_perm_b32 (values ~1e-4 vs 1e-2 threshold).
__device__ __forceinline__ unsigned int pk_bf16(float lo, float hi) {
    return __builtin_amdgcn_perm(__builtin_bit_cast(unsigned int, hi),
                                 __builtin_bit_cast(unsigned int, lo),
                                 0x07060302u);
}

// ws layout: [0..15] res f32. Then ushort region at ws+16:
//   w1t: W1^T bf16 [64][32]; w2t: W2^T k-permuted [64][64];
//   w3t: W3^T k-permuted row-replicated [16][64].
__global__ __launch_bounds__(256) void prep_kernel(
    const float* __restrict__ W1, const float* __restrict__ W2,
    const float* __restrict__ W3, float* __restrict__ ws, ResArr res)
{
    const int t = threadIdx.x;
    if (t < NLEV) ws[t] = res.r[t];
    unsigned short* w1t = (unsigned short*)(ws + 16);
    unsigned short* w2t = w1t + 64 * 32;
    unsigned short* w3t = w2t + 64 * 64;
    for (int i = t; i < 64 * 32; i += 256) {
        int n = i >> 5, k = i & 31;
        w1t[i] = bf16_rn(W1[k * 64 + n]);
    }
    for (int i = t; i < 64 * 64; i += 256) {
        int n2 = i >> 6, kp = i & 63;
        int klog = (kp & 32) | ((kp & 4) << 2) | ((kp & 24) >> 1) | (kp & 3);
        w2t[i] = bf16_rn(W2[klog * 64 + n2]);
    }
    for (int i = t; i < 16 * 64; i += 256) {
        int row = i >> 6, kp = i & 63;
        int klog = (kp & 32) | ((kp & 4) << 2) | ((kp & 24) >> 1) | (kp & 3);
        int ch = row & 3;
        w3t[i] = (ch < 3) ? bf16_rn(W3[klog * 3 + ch]) : (unsigned short)0;
    }
}

// Coarse-level staging geometry (levels 0..11, 16x16-px block):
// Wc_l = floor(15*res_l/1024) + 3 corners per axis (covers worst-case cell
// crossing +1 for the +1 corner). res = [16,21,27,36,48,63,84,111,147,194,
// 256,337] -> Wc = [3,3,3,3,3,3,4,4,5,5,6,7]; total corners = 221 (1.8 KB).
#define NCORN 221

// Fused kernel. Block = 4 waves over a 16x16-px tile; lane (c15 = l&15,
// g = l>>4) computes pixels (x=xb+c15, y=yb+wv*4+pt) at levels g*4+j.
// R5-R11 lesson: the encode is TA-request-throughput bound (~2.4 addr/cyc/CU;
// invariant to occupancy 34-62% and load-batch depth 2-32). So: levels 0-11
// (tiny per-block footprint) are staged once per block into LDS (221 loads)
// and bilerped from LDS by lanes g<3; only lanes g==3 (levels 12-15, truly
// random) issue per-pixel global gathers -> 16 active-lane loads/px vs 64.
// MLP: all three layers on MFMA, activations lane-local (k-permuted weights).
__global__ __launch_bounds__(256) void ngp_fused_kernel(
    const float* __restrict__ tables,
    const float* __restrict__ b1, const float* __restrict__ b2,
    const float* __restrict__ b3,
    const float* __restrict__ ws, float* __restrict__ out)
{
    __shared__ float2 ldsc[NCORN];

    const int tid  = threadIdx.x;
    const int lane = tid & 63;
    const int wv   = tid >> 6;
    const int c15  = lane & 15;
    const int g    = lane >> 4;
    const int xb   = blockIdx.x * 16;
    const int yb   = blockIdx.y * 16;

    constexpr int WCL[12]  = {3,3,3,3,3,3,4,4,5,5,6,7};
    constexpr int OFFL[12] = {0,9,18,27,36,45,54,70,86,111,136,172};

    const float xbf = (float)xb * (1.0f / 1024.0f);
    const float ybf = (float)yb * (1.0f / 1024.0f);

    // ---- stage coarse corners (levels 0..11) into LDS ----
    if (tid < NCORN) {
        #pragma unroll
        for (int l = 0; l < 12; ++l) {
            const int sz = WCL[l] * WCL[l];
            if (tid >= OFFL[l] && tid < OFFL[l] + sz) {
                const int local = tid - OFFL[l];
                const int jj = local / WCL[l];          // const divisor
                const int ii = local - jj * WCL[l];
                const float r = ws[l];
                const int cx0 = (int)floorf(xbf * r);   // exact: xb*r < 2^20
                const int cy0 = (int)floorf(ybf * r);
                const unsigned int idx =
                    (((unsigned int)(cx0 + ii)) ^
                     ((unsigned int)(cy0 + jj) * 2654435761u)) & TMASK;
                ldsc[tid] = ((const float2*)tables)[(size_t)l * TSIZE + idx];
            }
        }
    }
    __syncthreads();

    const float4 rv = *(const float4*)(ws + g * 4);
    const float rr[4] = { rv.x, rv.y, rv.z, rv.w };
    const float xs = (float)(xb + c15) * (1.0f / 1024.0f);
    float yf[4];
    #pragma unroll
    for (int pt = 0; pt < 4; ++pt)
        yf[pt] = (float)(yb + wv * 4 + pt) * (1.0f / 1024.0f);

    Frag bfrag[4];

    if (g < 3) {
        // ---- coarse path: bilerp levels g*4+j from LDS corner grids ----
        #pragma unroll
        for (int j = 0; j < 4; ++j) {
            const int lWc  = (g == 0) ? WCL[j]  : (g == 1) ? WCL[4 + j]  : WCL[8 + j];
            const int lOff = (g == 0) ? OFFL[j] : (g == 1) ? OFFL[4 + j] : OFFL[8 + j];
            const float r   = rr[j];
            const float sx  = xs * r;
            const float fx0 = floorf(sx);
            const float fx  = sx - fx0;
            const int ii    = (int)fx0 - (int)floorf(xbf * r);
            const int cy0i  = (int)floorf(ybf * r);
            #pragma unroll
            for (int pt = 0; pt < 4; ++pt) {
                const float sy  = yf[pt] * r;
                const float fy0 = floorf(sy);
                const float fy  = sy - fy0;
                const int jj    = (int)fy0 - cy0i;
                const int base  = lOff + jj * lWc + ii;
                const float2 c00 = ldsc[base];
                const float2 c10 = ldsc[base + 1];
                const float2 c01 = ldsc[base + lWc];
                const float2 c11 = ldsc[base + lWc + 1];
                const float w00 = (1.0f - fx) * (1.0f - fy);
                const float w10 = fx          * (1.0f - fy);
                const float w01 = (1.0f - fx) * fy;
                const float w11 = fx          * fy;
                bfrag[pt].u[j] = pk_bf16(
                    w00 * c00.x + w10 * c10.x + w01 * c01.x + w11 * c11.x,
                    w00 * c00.y + w10 * c10.y + w01 * c01.y + w11 * c11.y);
            }
        }
    } else {
        // ---- fine path (levels 12..15): per-pixel global gathers ----
        #pragma unroll
        for (int j = 0; j < 4; ++j) {
            const float r   = rr[j];
            const float sx  = xs * r;
            const float fx0 = floorf(sx);
            const float fx  = sx - fx0;
            const unsigned int cx  = (unsigned int)fx0;
            const unsigned int cx1 = cx + 1u;
            const float2* __restrict__ tab =
                (const float2*)tables + (size_t)(12 + j) * TSIZE;
            #pragma unroll
            for (int pt = 0; pt < 4; ++pt) {
                const float sy  = yf[pt] * r;
                const float fy0 = floorf(sy);
                const float fy  = sy - fy0;
                const unsigned int cy  = (unsigned int)fy0;
                const unsigned int hy0 = cy * 2654435761u;
                const unsigned int hy1 = hy0 + 2654435761u;
                const float2 f00 = tab[(cx  ^ hy0) & TMASK];
                const float2 f10 = tab[(cx1 ^ hy0) & TMASK];
                const float2 f01 = tab[(cx  ^ hy1) & TMASK];
                const float2 f11 = tab[(cx1 ^ hy1) & TMASK];
                const float w00 = (1.0f - fx) * (1.0f - fy);
                const float w10 = fx          * (1.0f - fy);
                const float w01 = (1.0f - fx) * fy;
                const float w11 = fx          * fy;
                bfrag[pt].u[j] = pk_bf16(
                    w00 * f00.x + w10 * f10.x + w01 * f01.x + w11 * f11.x,
                    w00 * f00.y + w10 * f10.y + w01 * f01.y + w11 * f11.y);
            }
        }
    }

    // ---- layer 1: bias+relu+pack into lane-local hp words ----
    const unsigned short* __restrict__ w1t = (const unsigned short*)(ws + 16);
    const unsigned short* __restrict__ w2t = w1t + 64 * 32;
    const unsigned short* __restrict__ w3t = w2t + 64 * 64;

    unsigned int hp[4][4][2];
    #pragma unroll
    for (int mt = 0; mt < 4; ++mt) {
        Frag afr;
        afr.v = *(const s8v*)(w1t + (mt * 16 + c15) * 32 + g * 8);
        const float4 bb = *(const float4*)(b1 + mt * 16 + g * 4);
        #pragma unroll
        for (int pt = 0; pt < 4; ++pt) {
            f4v acc = (f4v){0.f, 0.f, 0.f, 0.f};
            acc = __builtin_amdgcn_mfma_f32_16x16x32_bf16(
                afr.v, bfrag[pt].v, acc, 0, 0, 0);
            const float v0 = fmaxf(acc[0] + bb.x, 0.0f);
            const float v1 = fmaxf(acc[1] + bb.y, 0.0f);
            const float v2 = fmaxf(acc[2] + bb.z, 0.0f);
            const float v3 = fmaxf(acc[3] + bb.w, 0.0f);
            hp[mt][pt][0] = pk_bf16(v0, v1);
            hp[mt][pt][1] = pk_bf16(v2, v3);
        }
    }

    // ---- layer 2 (per-mt accumulator split, k-permuted W2) ----
    unsigned int hq[4][4][2];
    #pragma unroll
    for (int mt = 0; mt < 4; ++mt) {
        const float4 bb2 = *(const float4*)(b2 + mt * 16 + g * 4);
        f4v acc[4];
        #pragma unroll
        for (int pt = 0; pt < 4; ++pt) acc[pt] = (f4v){0.f, 0.f, 0.f, 0.f};
        #pragma unroll
        for (int st = 0; st < 2; ++st) {
            Frag a2, bf2[4];
            a2.v = *(const s8v*)(w2t + (mt * 16 + c15) * 64 + st * 32 + g * 8);
            #pragma unroll
            for (int pt = 0; pt < 4; ++pt) {
                bf2[pt].u[0] = hp[2 * st + 0][pt][0];
                bf2[pt].u[1] = hp[2 * st + 0][pt][1];
                bf2[pt].u[2] = hp[2 * st + 1][pt][0];
                bf2[pt].u[3] = hp[2 * st + 1][pt][1];
            }
            #pragma unroll
            for (int pt = 0; pt < 4; ++pt)
                acc[pt] = __builtin_amdgcn_mfma_f32_16x16x32_bf16(
                    a2.v, bf2[pt].v, acc[pt], 0, 0, 0);
        }
        #pragma unroll
        for (int pt = 0; pt < 4; ++pt) {
            const float v0 = fmaxf(acc[pt][0] + bb2.x, 0.0f);
            const float v1 = fmaxf(acc[pt][1] + bb2.y, 0.0f);
            const float v2 = fmaxf(acc[pt][2] + bb2.z, 0.0f);
            const float v3 = fmaxf(acc[pt][3] + bb2.w, 0.0f);
            hq[mt][pt][0] = pk_bf16(v0, v1);
            hq[mt][pt][1] = pk_bf16(v2, v3);
        }
    }

    // ---- layer 3 on MFMA (row-replicated W3: reg r = channel r) ----
    f4v acc3[4];
    #pragma unroll
    for (int pt = 0; pt < 4; ++pt) acc3[pt] = (f4v){0.f, 0.f, 0.f, 0.f};
    #pragma unroll
    for (int st = 0; st < 2; ++st) {
        Frag a3, bf3[4];
        a3.v = *(const s8v*)(w3t + c15 * 64 + st * 32 + g * 8);
        #pragma unroll
        for (int pt = 0; pt < 4; ++pt) {
            bf3[pt].u[0] = hq[2 * st + 0][pt][0];
            bf3[pt].u[1] = hq[2 * st + 0][pt][1];
            bf3[pt].u[2] = hq[2 * st + 1][pt][0];
            bf3[pt].u[3] = hq[2 * st + 1][pt][1];
        }
        #pragma unroll
        for (int pt = 0; pt < 4; ++pt)
            acc3[pt] = __builtin_amdgcn_mfma_f32_16x16x32_bf16(
                a3.v, bf3[pt].v, acc3[pt], 0, 0, 0);
    }

    float ov[3];
    #pragma unroll
    for (int c = 0; c < 3; ++c) {
        float v = acc3[0][c];
        v = (g == 1) ? acc3[1][c] : v;
        v = (g == 2) ? acc3[2][c] : v;
        v = (g == 3) ? acc3[3][c] : v;
        ov[c] = v + b3[c];
    }
    const int pix = ((yb + wv * 4 + g) << 10) + xb + c15;
    out[0 * NPIX + pix] = 1.0f / (1.0f + __expf(-ov[0]));
    out[1 * NPIX + pix] = 1.0f / (1.0f + __expf(-ov[1]));
    out[2 * NPIX + pix] = 1.0f / (1.0f + __expf(-ov[2]));
}

extern "C" void kernel_launch(void* const* d_in, const int* in_sizes, int n_in,
                              void* d_out, int out_size, void* d_ws, size_t ws_size,
                              hipStream_t stream) {
    const float* tables = (const float*)d_in[0];
    const float* W1     = (const float*)d_in[1];
    const float* b1     = (const float*)d_in[2];
    const float* W2     = (const float*)d_in[3];
    const float* b2     = (const float*)d_in[4];
    const float* W3     = (const float*)d_in[5];
    const float* b3     = (const float*)d_in[6];
    float* out          = (float*)d_out;
    float* ws           = (float*)d_ws;

    ResArr res;
    const double growth = exp((log(1024.0) - log(16.0)) / 15.0);
    for (int l = 0; l < NLEV; ++l)
        res.r[l] = (float)floor(16.0 * pow(growth, (double)l));

    hipLaunchKernelGGL(prep_kernel, dim3(1), dim3(256), 0, stream, W1, W2, W3, ws, res);
    hipLaunchKernelGGL(ngp_fused_kernel, dim3(64, 64), dim3(256), 0, stream,
                       tables, b1, b2, b3, ws, out);
}

// Round 13
// 73.535 us; speedup vs baseline: 1.0704x; 1.0510x over previous
//
#include <hip/hip_runtime.h>
#include <math.h>

#define NLEV   16
#define TSIZE  524288
#define TMASK  524287
#define NPIX   (1024*1024)

typedef __attribute__((ext_vector_type(8))) short s8v;
typedef __attribute__((ext_vector_type(4))) float f4v;

struct ResArr { float r[NLEV]; };
union Frag { unsigned int u[4]; s8v v; };

__device__ __forceinline__ unsigned short bf16_rn(float x) {
    unsigned int u = __builtin_bit_cast(unsigned int, x);
    u += 0x7fffu + ((u >> 16) & 1u);
    return (unsigned short)(u >> 16);
}
// truncating bf16 pack: one v_perm_b32 (values ~1e-4 vs 1e-2 threshold).
__device__ __forceinline__ unsigned int pk_bf16(float lo, float hi) {
    return __builtin_amdgcn_perm(__builtin_bit_cast(unsigned int, hi),
                                 __builtin_bit_cast(unsigned int, lo),
                                 0x07060302u);
}

// ws layout: [0..15] res f32. Then ushort region at ws+16:
//   w1t: W1^T bf16 [64][32]; w2t: W2^T k-permuted [64][64];
//   w3t: W3^T k-permuted row-replicated [16][64].
__global__ __launch_bounds__(256) void prep_kernel(
    const float* __restrict__ W1, const float* __restrict__ W2,
    const float* __restrict__ W3, float* __restrict__ ws, ResArr res)
{
    const int t = threadIdx.x;
    if (t < NLEV) ws[t] = res.r[t];
    unsigned short* w1t = (unsigned short*)(ws + 16);
    unsigned short* w2t = w1t + 64 * 32;
    unsigned short* w3t = w2t + 64 * 64;
    for (int i = t; i < 64 * 32; i += 256) {
        int n = i >> 5, k = i & 31;
        w1t[i] = bf16_rn(W1[k * 64 + n]);
    }
    for (int i = t; i < 64 * 64; i += 256) {
        int n2 = i >> 6, kp = i & 63;
        int klog = (kp & 32) | ((kp & 4) << 2) | ((kp & 24) >> 1) | (kp & 3);
        w2t[i] = bf16_rn(W2[klog * 64 + n2]);
    }
    for (int i = t; i < 16 * 64; i += 256) {
        int row = i >> 6, kp = i & 63;
        int klog = (kp & 32) | ((kp & 4) << 2) | ((kp & 24) >> 1) | (kp & 3);
        int ch = row & 3;
        w3t[i] = (ch < 3) ? bf16_rn(W3[klog * 3 + ch]) : (unsigned short)0;
    }
}

// Fine-level staging geometry (16x16-px block):
//   level 12 (res 445): Wc = floor(15*445/1024)+3 = 9   -> 81 corners
//   level 13 (res 588): Wc = floor(15*588/1024)+3 = 11  -> 121
//   level 14 (res 776): Wc = floor(15*776/1024)+3 = 14  -> 196
// total 398 corners = 3184 B. Level 15 (res 1024) is EXACT-INTEGER: scaled=x,
// frac=0 -> bilerp degenerates to 1 gather with weight 1 (other corners have
// exactly zero weight in the reference as well).
// R8-R12 evidence: encode floor (~45us) is invariant to occupancy (34-62%),
// load-batch depth (2-32), and active-lane request count (64->17/px, R12 null)
// -> it is unique-LINE fill traffic of the fine levels through the 4MB L2s.
// Staging 12-14 per block fetches each unique line once (~6x traffic cut);
// coarse levels 0-11 are L2-resident and stay per-pixel (R12: staging them
// only added overhead).
#define NFC 398

__global__ __launch_bounds__(256) void ngp_fused_kernel(
    const float* __restrict__ tables,
    const float* __restrict__ b1, const float* __restrict__ b2,
    const float* __restrict__ b3,
    const float* __restrict__ ws, float* __restrict__ out)
{
    __shared__ float2 ldsf[NFC];

    const int tid  = threadIdx.x;
    const int lane = tid & 63;
    const int wv   = tid >> 6;
    const int c15  = lane & 15;
    const int g    = lane >> 4;
    const int xb   = blockIdx.x * 16;
    const int yb   = blockIdx.y * 16;

    const float xbf = (float)xb * (1.0f / 1024.0f);
    const float ybf = (float)yb * (1.0f / 1024.0f);

    // ---- stage fine corners (levels 12..14) into LDS: 398 loads/block ----
    for (int i = tid; i < NFC; i += 256) {
        int l, loc, wc;
        if (i < 81)       { l = 0; loc = i;       wc = 9;  }
        else if (i < 202) { l = 1; loc = i - 81;  wc = 11; }
        else              { l = 2; loc = i - 202; wc = 14; }
        const int jj = loc / wc;
        const int ii = loc - jj * wc;
        const float r = ws[12 + l];
        const int cx0 = (int)floorf(xbf * r);   // exact: xb*r < 2^20
        const int cy0 = (int)floorf(ybf * r);
        const unsigned int idx =
            (((unsigned int)(cx0 + ii)) ^
             ((unsigned int)(cy0 + jj) * 2654435761u)) & TMASK;
        ldsf[i] = ((const float2*)tables)[(size_t)(12 + l) * TSIZE + idx];
    }
    __syncthreads();

    const float4 rv = *(const float4*)(ws + g * 4);
    const float rr[4] = { rv.x, rv.y, rv.z, rv.w };
    const float xs = (float)(xb + c15) * (1.0f / 1024.0f);
    float yf[4];
    #pragma unroll
    for (int pt = 0; pt < 4; ++pt)
        yf[pt] = (float)(yb + wv * 4 + pt) * (1.0f / 1024.0f);

    Frag bfrag[4];

    if (g < 3) {
        // ---- coarse path (levels g*4+j, j=0..3): per-pixel global gathers ----
        #pragma unroll
        for (int j = 0; j < 4; ++j) {
            const float r   = rr[j];
            const float sx  = xs * r;
            const float fx0 = floorf(sx);
            const float fx  = sx - fx0;
            const unsigned int cx  = (unsigned int)fx0;
            const unsigned int cx1 = cx + 1u;
            const float2* __restrict__ tab =
                (const float2*)tables + (size_t)(g * 4 + j) * TSIZE;
            #pragma unroll
            for (int pt = 0; pt < 4; ++pt) {
                const float sy  = yf[pt] * r;
                const float fy0 = floorf(sy);
                const float fy  = sy - fy0;
                const unsigned int cy  = (unsigned int)fy0;
                const unsigned int hy0 = cy * 2654435761u;
                const unsigned int hy1 = hy0 + 2654435761u;
                const float2 f00 = tab[(cx  ^ hy0) & TMASK];
                const float2 f10 = tab[(cx1 ^ hy0) & TMASK];
                const float2 f01 = tab[(cx  ^ hy1) & TMASK];
                const float2 f11 = tab[(cx1 ^ hy1) & TMASK];
                const float w00 = (1.0f - fx) * (1.0f - fy);
                const float w10 = fx          * (1.0f - fy);
                const float w01 = (1.0f - fx) * fy;
                const float w11 = fx          * fy;
                bfrag[pt].u[j] = pk_bf16(
                    w00 * f00.x + w10 * f10.x + w01 * f01.x + w11 * f11.x,
                    w00 * f00.y + w10 * f10.y + w01 * f01.y + w11 * f11.y);
            }
        }
    } else {
        // ---- fine path: levels 12..14 from LDS, level 15 single gather ----
        const int FWC[3]  = {9, 11, 14};
        const int FOFF[3] = {0, 81, 202};
        #pragma unroll
        for (int j = 0; j < 3; ++j) {
            const int wc  = FWC[j];
            const int off = FOFF[j];
            const float r   = rr[j];
            const float sx  = xs * r;
            const float fx0 = floorf(sx);
            const float fx  = sx - fx0;
            const int ii    = (int)fx0 - (int)floorf(xbf * r);
            const int cy0i  = (int)floorf(ybf * r);
            #pragma unroll
            for (int pt = 0; pt < 4; ++pt) {
                const float sy  = yf[pt] * r;
                const float fy0 = floorf(sy);
                const float fy  = sy - fy0;
                const int jj    = (int)fy0 - cy0i;
                const int base  = off + jj * wc + ii;
                const float2 c00 = ldsf[base];
                const float2 c10 = ldsf[base + 1];
                const float2 c01 = ldsf[base + wc];
                const float2 c11 = ldsf[base + wc + 1];
                const float w00 = (1.0f - fx) * (1.0f - fy);
                const float w10 = fx          * (1.0f - fy);
                const float w01 = (1.0f - fx) * fy;
                const float w11 = fx          * fy;
                bfrag[pt].u[j] = pk_bf16(
                    w00 * c00.x + w10 * c10.x + w01 * c01.x + w11 * c11.x,
                    w00 * c00.y + w10 * c10.y + w01 * c01.y + w11 * c11.y);
            }
        }
        // level 15: scaled == integer pixel coords exactly -> weight-1 corner
        {
            const float2* __restrict__ tab =
                (const float2*)tables + (size_t)15 * TSIZE;
            const unsigned int cx = (unsigned int)(xb + c15);
            #pragma unroll
            for (int pt = 0; pt < 4; ++pt) {
                const unsigned int cy = (unsigned int)(yb + wv * 4 + pt);
                const float2 f00 = tab[(cx ^ (cy * 2654435761u)) & TMASK];
                bfrag[pt].u[3] = pk_bf16(f00.x, f00.y);
            }
        }
    }

    // ---- layer 1: bias+relu+pack into lane-local hp words ----
    const unsigned short* __restrict__ w1t = (const unsigned short*)(ws + 16);
    const unsigned short* __restrict__ w2t = w1t + 64 * 32;
    const unsigned short* __restrict__ w3t = w2t + 64 * 64;

    unsigned int hp[4][4][2];
    #pragma unroll
    for (int mt = 0; mt < 4; ++mt) {
        Frag afr;
        afr.v = *(const s8v*)(w1t + (mt * 16 + c15) * 32 + g * 8);
        const float4 bb = *(const float4*)(b1 + mt * 16 + g * 4);
        #pragma unroll
        for (int pt = 0; pt < 4; ++pt) {
            f4v acc = (f4v){0.f, 0.f, 0.f, 0.f};
            acc = __builtin_amdgcn_mfma_f32_16x16x32_bf16(
                afr.v, bfrag[pt].v, acc, 0, 0, 0);
            const float v0 = fmaxf(acc[0] + bb.x, 0.0f);
            const float v1 = fmaxf(acc[1] + bb.y, 0.0f);
            const float v2 = fmaxf(acc[2] + bb.z, 0.0f);
            const float v3 = fmaxf(acc[3] + bb.w, 0.0f);
            hp[mt][pt][0] = pk_bf16(v0, v1);
            hp[mt][pt][1] = pk_bf16(v2, v3);
        }
    }

    // ---- layer 2 (per-mt accumulator split, k-permuted W2) ----
    unsigned int hq[4][4][2];
    #pragma unroll
    for (int mt = 0; mt < 4; ++mt) {
        const float4 bb2 = *(const float4*)(b2 + mt * 16 + g * 4);
        f4v acc[4];
        #pragma unroll
        for (int pt = 0; pt < 4; ++pt) acc[pt] = (f4v){0.f, 0.f, 0.f, 0.f};
        #pragma unroll
        for (int st = 0; st < 2; ++st) {
            Frag a2, bf2[4];
            a2.v = *(const s8v*)(w2t + (mt * 16 + c15) * 64 + st * 32 + g * 8);
            #pragma unroll
            for (int pt = 0; pt < 4; ++pt) {
                bf2[pt].u[0] = hp[2 * st + 0][pt][0];
                bf2[pt].u[1] = hp[2 * st + 0][pt][1];
                bf2[pt].u[2] = hp[2 * st + 1][pt][0];
                bf2[pt].u[3] = hp[2 * st + 1][pt][1];
            }
            #pragma unroll
            for (int pt = 0; pt < 4; ++pt)
                acc[pt] = __builtin_amdgcn_mfma_f32_16x16x32_bf16(
                    a2.v, bf2[pt].v, acc[pt], 0, 0, 0);
        }
        #pragma unroll
        for (int pt = 0; pt < 4; ++pt) {
            const float v0 = fmaxf(acc[pt][0] + bb2.x, 0.0f);
            const float v1 = fmaxf(acc[pt][1] + bb2.y, 0.0f);
            const float v2 = fmaxf(acc[pt][2] + bb2.z, 0.0f);
            const float v3 = fmaxf(acc[pt][3] + bb2.w, 0.0f);
            hq[mt][pt][0] = pk_bf16(v0, v1);
            hq[mt][pt][1] = pk_bf16(v2, v3);
        }
    }

    // ---- layer 3 on MFMA (row-replicated W3: reg r = channel r) ----
    f4v acc3[4];
    #pragma unroll
    for (int pt = 0; pt < 4; ++pt) acc3[pt] = (f4v){0.f, 0.f, 0.f, 0.f};
    #pragma unroll
    for (int st = 0; st < 2; ++st) {
        Frag a3, bf3[4];
        a3.v = *(const s8v*)(w3t + c15 * 64 + st * 32 + g * 8);
        #pragma unroll
        for (int pt = 0; pt < 4; ++pt) {
            bf3[pt].u[0] = hq[2 * st + 0][pt][0];
            bf3[pt].u[1] = hq[2 * st + 0][pt][1];
            bf3[pt].u[2] = hq[2 * st + 1][pt][0];
            bf3[pt].u[3] = hq[2 * st + 1][pt][1];
        }
        #pragma unroll
        for (int pt = 0; pt < 4; ++pt)
            acc3[pt] = __builtin_amdgcn_mfma_f32_16x16x32_bf16(
                a3.v, bf3[pt].v, acc3[pt], 0, 0, 0);
    }

    float ov[3];
    #pragma unroll
    for (int c = 0; c < 3; ++c) {
        float v = acc3[0][c];
        v = (g == 1) ? acc3[1][c] : v;
        v = (g == 2) ? acc3[2][c] : v;
        v = (g == 3) ? acc3[3][c] : v;
        ov[c] = v + b3[c];
    }
    const int pix = ((yb + wv * 4 + g) << 10) + xb + c15;
    out[0 * NPIX + pix] = 1.0f / (1.0f + __expf(-ov[0]));
    out[1 * NPIX + pix] = 1.0f / (1.0f + __expf(-ov[1]));
    out[2 * NPIX + pix] = 1.0f / (1.0f + __expf(-ov[2]));
}

extern "C" void kernel_launch(void* const* d_in, const int* in_sizes, int n_in,
                              void* d_out, int out_size, void* d_ws, size_t ws_size,
                              hipStream_t stream) {
    const float* tables = (const float*)d_in[0];
    const float* W1     = (const float*)d_in[1];
    const float* b1     = (const float*)d_in[2];
    const float* W2     = (const float*)d_in[3];
    const float* b2     = (const float*)d_in[4];
    const float* W3     = (const float*)d_in[5];
    const float* b3     = (const float*)d_in[6];
    float* out          = (float*)d_out;
    float* ws           = (float*)d_ws;

    ResArr res;
    const double growth = exp((log(1024.0) - log(16.0)) / 15.0);
    for (int l = 0; l < NLEV; ++l)
        res.r[l] = (float)floor(16.0 * pow(growth, (double)l));

    hipLaunchKernelGGL(prep_kernel, dim3(1), dim3(256), 0, stream, W1, W2, W3, ws, res);
    hipLaunchKernelGGL(ngp_fused_kernel, dim3(64, 64), dim3(256), 0, stream,
                       tables, b1, b2, b3, ws, out);
}

// Round 14
// 68.022 us; speedup vs baseline: 1.1571x; 1.0810x over previous
//
#include <hip/hip_runtime.h>
#include <math.h>

#define NLEV   16
#define TSIZE  524288
#define TMASK8 0x3FFFF8u        // (TSIZE-1) << 3, byte-space hash mask
#define PRIME8 4055616904u      // (2654435761 * 8) mod 2^32, byte-space prime
#define NPIX   (1024*1024)

typedef __attribute__((ext_vector_type(8))) short s8v;
typedef __attribute__((ext_vector_type(4))) float f4v;
typedef __attribute__((ext_vector_type(2))) float f2v;

struct ResArr { float r[NLEV]; };
union Frag { unsigned int u[4]; s8v v; };

__device__ __forceinline__ unsigned short bf16_rn(float x) {
    unsigned int u = __builtin_bit_cast(unsigned int, x);
    u += 0x7fffu + ((u >> 16) & 1u);
    return (unsigned short)(u >> 16);
}
// truncating bf16 pack: one v_perm_b32 (values ~1e-4 vs 1e-2 threshold).
__device__ __forceinline__ unsigned int pk_bf16(float lo, float hi) {
    return __builtin_amdgcn_perm(__builtin_bit_cast(unsigned int, hi),
                                 __builtin_bit_cast(unsigned int, lo),
                                 0x07060302u);
}

// ws layout: [0..15] res f32. Then ushort region at ws+16:
//   w1t: W1^T bf16 [64][32]; w2t: W2^T k-permuted [64][64];
//   w3t: W3^T k-permuted row-replicated [16][64].
// k-permutation: physical k bits [st|g1 g0|j2 j1 j0] hold logical
// [st|j2|g1 g0|j1 j0] so each layer's B-fragments are the lane's own
// previous-layer output words (no LDS/shuffle exchange).
__global__ __launch_bounds__(256) void prep_kernel(
    const float* __restrict__ W1, const float* __restrict__ W2,
    const float* __restrict__ W3, float* __restrict__ ws, ResArr res)
{
    const int t = threadIdx.x;
    if (t < NLEV) ws[t] = res.r[t];
    unsigned short* w1t = (unsigned short*)(ws + 16);
    unsigned short* w2t = w1t + 64 * 32;
    unsigned short* w3t = w2t + 64 * 64;
    for (int i = t; i < 64 * 32; i += 256) {
        int n = i >> 5, k = i & 31;
        w1t[i] = bf16_rn(W1[k * 64 + n]);
    }
    for (int i = t; i < 64 * 64; i += 256) {
        int n2 = i >> 6, kp = i & 63;
        int klog = (kp & 32) | ((kp & 4) << 2) | ((kp & 24) >> 1) | (kp & 3);
        w2t[i] = bf16_rn(W2[klog * 64 + n2]);
    }
    for (int i = t; i < 16 * 64; i += 256) {
        int row = i >> 6, kp = i & 63;
        int klog = (kp & 32) | ((kp & 4) << 2) | ((kp & 24) >> 1) | (kp & 3);
        int ch = row & 3;
        w3t[i] = (ch < 3) ? bf16_rn(W3[klog * 3 + ch]) : (unsigned short)0;
    }
}

// R8 structure (best base, no divergence/staging) with the VALU stream
// halved; gather instruction count/addresses identical to R8:
//  - byte-space hash: pre-shifted prime kills the per-corner <<3; (x & M)|lb
//    folds to v_and_or_b32.
//  - lerp-form bilerp on f2v ext-vectors -> v_pk_*_f32 (6 pk ops vs ~14
//    scalar per (j,pt)).
//  - f4v packed bias+relu epilogues (pk_add/pk_max).
//  - layer outputs written directly into next layer's B-fragment Frags
//    (hp2/hq2[st][pt]) -> the 64 assembly movs become register renames.
// Discriminator: if dur doesn't move, the encode floor is TA lane-slot
// throughput (gather instructions unchanged) -> structural.
__global__ __launch_bounds__(256) void ngp_fused_kernel(
    const float* __restrict__ tables,
    const float* __restrict__ b1, const float* __restrict__ b2,
    const float* __restrict__ b3,
    const float* __restrict__ ws, float* __restrict__ out)
{
    const int tid  = threadIdx.x;
    const int lane = tid & 63;
    const int wv   = tid >> 6;
    const int c15  = lane & 15;
    const int g    = lane >> 4;
    const int xb   = blockIdx.x * 16;
    const int yb   = blockIdx.y * 16;

    const float4 rv = *(const float4*)(ws + g * 4);
    const float rr[4] = { rv.x, rv.y, rv.z, rv.w };
    const float xs = (float)(xb + c15) * (1.0f / 1024.0f);
    float yf[4];
    #pragma unroll
    for (int pt = 0; pt < 4; ++pt)
        yf[pt] = (float)(yb + wv * 4 + pt) * (1.0f / 1024.0f);

    const char* __restrict__ tb = (const char*)tables;   // wave-uniform base
    const unsigned int lvlb = (unsigned int)(g * 4) << 22;  // 4 MB per level

    // ---- encode: 16 levels x 4 corners, byte-space hash + packed bilerp ----
    Frag bfrag[4];
    #pragma unroll
    for (int j = 0; j < 4; ++j) {
        const float r   = rr[j];
        const float sx  = xs * r;
        const float fx0 = floorf(sx);
        const float fx  = sx - fx0;
        const f2v  fx2  = { fx, fx };
        const unsigned int cx8  = ((unsigned int)(int)fx0) << 3;
        const unsigned int cx8b = cx8 + 8u;
        const unsigned int lb   = lvlb + ((unsigned int)j << 22);
        #pragma unroll
        for (int pt = 0; pt < 4; ++pt) {
            const float sy  = yf[pt] * r;
            const float fy0 = floorf(sy);
            const float fy  = sy - fy0;
            const f2v  fy2  = { fy, fy };
            const unsigned int cy  = (unsigned int)(int)fy0;
            const unsigned int hy0 = cy * PRIME8;
            const unsigned int hy1 = hy0 + PRIME8;
            const f2v c00 = *(const f2v*)(tb + (((cx8  ^ hy0) & TMASK8) | lb));
            const f2v c10 = *(const f2v*)(tb + (((cx8b ^ hy0) & TMASK8) | lb));
            const f2v c01 = *(const f2v*)(tb + (((cx8  ^ hy1) & TMASK8) | lb));
            const f2v c11 = *(const f2v*)(tb + (((cx8b ^ hy1) & TMASK8) | lb));
            const f2v top = c00 + fx2 * (c10 - c00);
            const f2v bot = c01 + fx2 * (c11 - c01);
            const f2v e   = top + fy2 * (bot - top);
            bfrag[pt].u[j] = pk_bf16(e[0], e[1]);
        }
    }

    const unsigned short* __restrict__ w1t = (const unsigned short*)(ws + 16);
    const unsigned short* __restrict__ w2t = w1t + 64 * 32;
    const unsigned short* __restrict__ w3t = w2t + 64 * 64;
    const f4v zero4 = { 0.f, 0.f, 0.f, 0.f };

    // ---- layer 1: packed epilogue, write straight into layer-2 B-frags ----
    Frag hp2[2][4];   // [st][pt]
    #pragma unroll
    for (int mt = 0; mt < 4; ++mt) {
        Frag afr;
        afr.v = *(const s8v*)(w1t + (mt * 16 + c15) * 32 + g * 8);
        const f4v bb = *(const f4v*)(b1 + mt * 16 + g * 4);
        #pragma unroll
        for (int pt = 0; pt < 4; ++pt) {
            f4v acc = zero4;
            acc = __builtin_amdgcn_mfma_f32_16x16x32_bf16(
                afr.v, bfrag[pt].v, acc, 0, 0, 0);
            const f4v hv = __builtin_elementwise_max(acc + bb, zero4);
            hp2[mt >> 1][pt].u[(mt & 1) * 2 + 0] = pk_bf16(hv[0], hv[1]);
            hp2[mt >> 1][pt].u[(mt & 1) * 2 + 1] = pk_bf16(hv[2], hv[3]);
        }
    }

    // ---- layer 2: B-frags are hp2[st][pt] directly (k-permuted W2) ----
    Frag hq2[2][4];
    #pragma unroll
    for (int mt = 0; mt < 4; ++mt) {
        const f4v bb2 = *(const f4v*)(b2 + mt * 16 + g * 4);
        f4v acc[4] = { zero4, zero4, zero4, zero4 };
        #pragma unroll
        for (int st = 0; st < 2; ++st) {
            Frag a2;
            a2.v = *(const s8v*)(w2t + (mt * 16 + c15) * 64 + st * 32 + g * 8);
            #pragma unroll
            for (int pt = 0; pt < 4; ++pt)
                acc[pt] = __builtin_amdgcn_mfma_f32_16x16x32_bf16(
                    a2.v, hp2[st][pt].v, acc[pt], 0, 0, 0);
        }
        #pragma unroll
        for (int pt = 0; pt < 4; ++pt) {
            const f4v hv = __builtin_elementwise_max(acc[pt] + bb2, zero4);
            hq2[mt >> 1][pt].u[(mt & 1) * 2 + 0] = pk_bf16(hv[0], hv[1]);
            hq2[mt >> 1][pt].u[(mt & 1) * 2 + 1] = pk_bf16(hv[2], hv[3]);
        }
    }

    // ---- layer 3 on MFMA (row-replicated W3: reg r = channel r) ----
    f4v acc3[4] = { zero4, zero4, zero4, zero4 };
    #pragma unroll
    for (int st = 0; st < 2; ++st) {
        Frag a3;
        a3.v = *(const s8v*)(w3t + c15 * 64 + st * 32 + g * 8);
        #pragma unroll
        for (int pt = 0; pt < 4; ++pt)
            acc3[pt] = __builtin_amdgcn_mfma_f32_16x16x32_bf16(
                a3.v, hq2[st][pt].v, acc3[pt], 0, 0, 0);
    }

    float ov[3];
    #pragma unroll
    for (int c = 0; c < 3; ++c) {
        float v = acc3[0][c];
        v = (g == 1) ? acc3[1][c] : v;
        v = (g == 2) ? acc3[2][c] : v;
        v = (g == 3) ? acc3[3][c] : v;
        ov[c] = v + b3[c];
    }
    const int pix = ((yb + wv * 4 + g) << 10) + xb + c15;
    out[0 * NPIX + pix] = 1.0f / (1.0f + __expf(-ov[0]));
    out[1 * NPIX + pix] = 1.0f / (1.0f + __expf(-ov[1]));
    out[2 * NPIX + pix] = 1.0f / (1.0f + __expf(-ov[2]));
}

extern "C" void kernel_launch(void* const* d_in, const int* in_sizes, int n_in,
                              void* d_out, int out_size, void* d_ws, size_t ws_size,
                              hipStream_t stream) {
    const float* tables = (const float*)d_in[0];
    const float* W1     = (const float*)d_in[1];
    const float* b1     = (const float*)d_in[2];
    const float* W2     = (const float*)d_in[3];
    const float* b2     = (const float*)d_in[4];
    const float* W3     = (const float*)d_in[5];
    const float* b3     = (const float*)d_in[6];
    float* out          = (float*)d_out;
    float* ws           = (float*)d_ws;

    ResArr res;
    const double growth = exp((log(1024.0) - log(16.0)) / 15.0);
    for (int l = 0; l < NLEV; ++l)
        res.r[l] = (float)floor(16.0 * pow(growth, (double)l));

    hipLaunchKernelGGL(prep_kernel, dim3(1), dim3(256), 0, stream, W1, W2, W3, ws, res);
    hipLaunchKernelGGL(ngp_fused_kernel, dim3(64, 64), dim3(256), 0, stream,
                       tables, b1, b2, b3, ws, out);
}